// Round 18
// baseline (43.996 us; speedup 1.0000x reference)
//
#include <hip/hip_runtime.h>
#include <math.h>

#define DIMS 3
#define NPTS 320
#define HID  128
#define RANK 64
#define CH   160   // c rows per block (half of NPTS)
#define LROW 128   // LDS bytes per c row (single bf16 table), XOR-swizzled

typedef __attribute__((ext_vector_type(8)))  short bf16x8;
typedef __attribute__((ext_vector_type(16))) float f32x16;

// round-to-nearest-even float -> bf16 bits
static __device__ __forceinline__ unsigned short f2bf_rn(float x) {
    union { float f; unsigned int u; } v; v.f = x;
    unsigned int r = v.u + 0x7fffu + ((v.u >> 16) & 1u);
    return (unsigned short)(r >> 16);
}
static __device__ __forceinline__ float bf2f(unsigned short h) {
    union { unsigned int u; float f; } v; v.u = ((unsigned int)h) << 16;
    return v.f;
}

// ---------------- Phase 1: per-dim MLP, 4-way k-split (R14, proven best) ----
__global__ __launch_bounds__(512)
void mlp_kernel(const float* __restrict__ xs,
                const float* __restrict__ W0, const float* __restrict__ b0,
                const float* __restrict__ W1, const float* __restrict__ b1,
                const float* __restrict__ W2, const float* __restrict__ b2,
                const float* __restrict__ W3, const float* __restrict__ b3,
                float* __restrict__ f01t,
                unsigned short* __restrict__ f2hi) {
    const int blk = blockIdx.x;
    const int d = blk / NPTS, n = blk % NPTS;
    const int j  = threadIdx.x & (HID - 1);
    const int kq = threadIdx.x >> 7;          // 0..3
    const int k0 = kq * 32;

    __shared__ float ha[HID];
    __shared__ float hb[HID];
    __shared__ float part[4][HID];

    const float x = xs[d * NPTS + n];

    if (kq == 0) {
        ha[j] = tanhf(fmaf(x, W0[d * HID + j], b0[d * HID + j]));
    }
    __syncthreads();

    {
        float acc = 0.0f;
        const float* w = W1 + d * HID * HID + j;
        #pragma unroll 16
        for (int k = 0; k < 32; ++k) acc = fmaf(ha[k0 + k], w[(k0 + k) * HID], acc);
        part[kq][j] = acc;
    }
    __syncthreads();
    if (kq == 0) {
        float s = ((part[0][j] + part[1][j]) + (part[2][j] + part[3][j]))
                  + b1[d * HID + j];
        hb[j] = tanhf(s);
    }
    __syncthreads();

    {
        float acc = 0.0f;
        const float* w = W2 + d * HID * HID + j;
        #pragma unroll 16
        for (int k = 0; k < 32; ++k) acc = fmaf(hb[k0 + k], w[(k0 + k) * HID], acc);
        part[kq][j] = acc;
    }
    __syncthreads();
    if (kq == 0) {
        float s = ((part[0][j] + part[1][j]) + (part[2][j] + part[3][j]))
                  + b2[d * HID + j];
        ha[j] = tanhf(s);
    }
    __syncthreads();

    if (j < RANK) {
        float acc = 0.0f;
        const float* w = W3 + d * HID * RANK + j;
        #pragma unroll 16
        for (int k = 0; k < 32; ++k) acc = fmaf(ha[k0 + k], w[(k0 + k) * RANK], acc);
        part[kq][j] = acc;
    }
    __syncthreads();
    if (kq == 0 && j < RANK) {
        float s = ((part[0][j] + part[1][j]) + (part[2][j] + part[3][j]))
                  + b3[d * RANK + j];
        if (d == 0) {
            f01t[n * RANK + j] = s;                      // f0t[a][r]
        } else if (d == 1) {
            f01t[(NPTS + n) * RANK + j] = s;             // f1t[b][r]
        } else {
            f2hi[n * RANK + j] = f2bf_rn(s);             // single-rounded B
        }
    }
}

// ---------------- Phase 2: persistent-block CP via 32x32x16 bf16 MFMA -------
// R14 structure with MFMA operand roles SWAPPED: A = f2 (row=c, from the
// SAME swizzled LDS read), B = g = f0*f1 (col=b, SAME in-register build).
// D: col(b)=lane, row(c)=reg -> each lane holds 4 consecutive c per reg-quad
// => epilogue is 4 float4 (dwordx4) stores per ct instead of 16 scalar dword
// stores. 4x fewer store instructions, same bytes, same interleaved
// no-barrier structure, numerically identical hi/lo sum.
__global__ __launch_bounds__(128, 2)
void cp_mfma_kernel(const float* __restrict__ f01t,
                    const unsigned short* __restrict__ f2hi,
                    float* __restrict__ out) {
    const int tx = threadIdx.x;
    const int w  = tx >> 6;        // wave -> b sub-tile
    const int l  = tx & 63;
    const int lc = l & 31;         // B col(b) / A row(c) / D col(b)
    const int hw = l >> 5;         // half-wave -> k sub-group

    const int c0 = (blockIdx.x & 1) * CH;

    __shared__ char sB[CH * LROW];   // 20 KB

    // ---- stage c-half of f2 once (1280 float4, 10/thread), swizzled ----
    #pragma unroll
    for (int i = 0; i < 10; ++i) {
        int idx = tx + i * 128;               // 0..1279
        int row = idx >> 3;                   // local c row
        int g   = (idx & 7) << 4;             // 16B slot within 128B row
        *(float4*)(&sB[row * LROW + (g ^ ((row & 7) << 4))]) =
            ((const float4*)f2hi)[c0 * 8 + idx];
    }
    __syncthreads();

    for (int t = blockIdx.x >> 1; t < NPTS * 5; t += 512) {
        const int a   = t / 5;
        const int b0w = (t - a * 5) * 64 + w * 32;
        const float* f0p = f01t + (size_t)a * RANK + hw * 8;
        const float* f1p = f01t + (size_t)(NPTS + b0w + lc) * RANK + hw * 8;

        // ---- B fragments (g): g[j] = f0[a][k]*f1[b][k], k = ks*16+hw*8+j ----
        bf16x8 ghi[4], glo[4];
        #pragma unroll
        for (int ks = 0; ks < 4; ++ks) {
            const int k0 = ks * 16;
            float4 f0a = *(const float4*)(f0p + k0);
            float4 f0b = *(const float4*)(f0p + k0 + 4);
            float4 f1a = *(const float4*)(f1p + k0);
            float4 f1b = *(const float4*)(f1p + k0 + 4);

            float g[8];
            g[0] = f1a.x * f0a.x; g[1] = f1a.y * f0a.y;
            g[2] = f1a.z * f0a.z; g[3] = f1a.w * f0a.w;
            g[4] = f1b.x * f0b.x; g[5] = f1b.y * f0b.y;
            g[6] = f1b.z * f0b.z; g[7] = f1b.w * f0b.w;

            #pragma unroll
            for (int j = 0; j < 8; ++j) {
                unsigned short hi = f2bf_rn(g[j]);
                ghi[ks][j] = (short)hi;
                glo[ks][j] = (short)f2bf_rn(g[j] - bf2f(hi));
            }
        }

        // ---- 5 c-tiles of 32: 4 LDS reads (A=f2) + 8 MFMAs + 4 float4 stores
        #pragma unroll
        for (int ct = 0; ct < 5; ++ct) {
            const char* rowp = &sB[(ct * 32 + lc) * LROW];
            const int swz = ((ct * 32 + lc) & 7) << 4;

            f32x16 acc;
            #pragma unroll
            for (int jj = 0; jj < 16; ++jj) acc[jj] = 0.0f;

            #pragma unroll
            for (int ks = 0; ks < 4; ++ks) {
                const int base = ks * 32 + (hw << 4);       // k slot bytes
                bf16x8 fa = *(const bf16x8*)(rowp + (base ^ swz));  // A: f2[c][k]
                acc = __builtin_amdgcn_mfma_f32_32x32x16_bf16(fa, ghi[ks], acc, 0, 0, 0);
                acc = __builtin_amdgcn_mfma_f32_32x32x16_bf16(fa, glo[ks], acc, 0, 0, 0);
            }

            // D: col(b)=lc, row(c) = (q&3) + 8*(q>>2) + 4*hw
            // lane stores 4 float4 = consecutive c runs at c0+ct*32+8*qq+4*hw
            float* obase = out + ((size_t)a * NPTS + b0w + lc) * NPTS
                           + c0 + ct * 32 + 4 * hw;
            #pragma unroll
            for (int qq = 0; qq < 4; ++qq) {
                float4 v;
                v.x = acc[4 * qq + 0];
                v.y = acc[4 * qq + 1];
                v.z = acc[4 * qq + 2];
                v.w = acc[4 * qq + 3];
                *(float4*)(&obase[8 * qq]) = v;
            }
        }
    }
}

extern "C" void kernel_launch(void* const* d_in, const int* in_sizes, int n_in,
                              void* d_out, int out_size, void* d_ws, size_t ws_size,
                              hipStream_t stream) {
    const float* xs = (const float*)d_in[0];
    const float* W0 = (const float*)d_in[1];
    const float* b0 = (const float*)d_in[2];
    const float* W1 = (const float*)d_in[3];
    const float* b1 = (const float*)d_in[4];
    const float* W2 = (const float*)d_in[5];
    const float* b2 = (const float*)d_in[6];
    const float* W3 = (const float*)d_in[7];
    const float* b3 = (const float*)d_in[8];

    // workspace: f01t float[2][NPTS][RANK] | f2hi ushort[NPTS][RANK]
    float* f01t = (float*)d_ws;
    unsigned short* f2hi = (unsigned short*)((char*)d_ws + 2 * NPTS * RANK * 4);
    float* out = (float*)d_out;

    mlp_kernel<<<dim3(DIMS * NPTS), dim3(512), 0, stream>>>(
        xs, W0, b0, W1, b1, W2, b2, W3, b3, f01t, f2hi);

    cp_mfma_kernel<<<dim3(1024), dim3(128), 0, stream>>>(f01t, f2hi, out);
}

// Round 19
// 37.899 us; speedup vs baseline: 1.1609x; 1.1609x over previous
//
#include <hip/hip_runtime.h>
#include <math.h>

#define DIMS 3
#define NPTS 320
#define HID  128
#define RANK 64
#define CH   160   // c rows per block (half of NPTS)
#define LROW 128   // LDS bytes per c row (single bf16 table), XOR-swizzled

typedef __attribute__((ext_vector_type(8)))  short bf16x8;
typedef __attribute__((ext_vector_type(16))) float f32x16;

// round-to-nearest-even float -> bf16 bits
static __device__ __forceinline__ unsigned short f2bf_rn(float x) {
    union { float f; unsigned int u; } v; v.f = x;
    unsigned int r = v.u + 0x7fffu + ((v.u >> 16) & 1u);
    return (unsigned short)(r >> 16);
}
static __device__ __forceinline__ float bf2f(unsigned short h) {
    union { unsigned int u; float f; } v; v.u = ((unsigned int)h) << 16;
    return v.f;
}

// ---------------- Phase 1: per-dim MLP, 4-way k-split (R14, proven best) ----
__global__ __launch_bounds__(512)
void mlp_kernel(const float* __restrict__ xs,
                const float* __restrict__ W0, const float* __restrict__ b0,
                const float* __restrict__ W1, const float* __restrict__ b1,
                const float* __restrict__ W2, const float* __restrict__ b2,
                const float* __restrict__ W3, const float* __restrict__ b3,
                float* __restrict__ f01t,
                unsigned short* __restrict__ f2hi) {
    const int blk = blockIdx.x;
    const int d = blk / NPTS, n = blk % NPTS;
    const int j  = threadIdx.x & (HID - 1);
    const int kq = threadIdx.x >> 7;          // 0..3
    const int k0 = kq * 32;

    __shared__ float ha[HID];
    __shared__ float hb[HID];
    __shared__ float part[4][HID];

    const float x = xs[d * NPTS + n];

    if (kq == 0) {
        ha[j] = tanhf(fmaf(x, W0[d * HID + j], b0[d * HID + j]));
    }
    __syncthreads();

    {
        float acc = 0.0f;
        const float* w = W1 + d * HID * HID + j;
        #pragma unroll 16
        for (int k = 0; k < 32; ++k) acc = fmaf(ha[k0 + k], w[(k0 + k) * HID], acc);
        part[kq][j] = acc;
    }
    __syncthreads();
    if (kq == 0) {
        float s = ((part[0][j] + part[1][j]) + (part[2][j] + part[3][j]))
                  + b1[d * HID + j];
        hb[j] = tanhf(s);
    }
    __syncthreads();

    {
        float acc = 0.0f;
        const float* w = W2 + d * HID * HID + j;
        #pragma unroll 16
        for (int k = 0; k < 32; ++k) acc = fmaf(hb[k0 + k], w[(k0 + k) * HID], acc);
        part[kq][j] = acc;
    }
    __syncthreads();
    if (kq == 0) {
        float s = ((part[0][j] + part[1][j]) + (part[2][j] + part[3][j]))
                  + b2[d * HID + j];
        ha[j] = tanhf(s);
    }
    __syncthreads();

    if (j < RANK) {
        float acc = 0.0f;
        const float* w = W3 + d * HID * RANK + j;
        #pragma unroll 16
        for (int k = 0; k < 32; ++k) acc = fmaf(ha[k0 + k], w[(k0 + k) * RANK], acc);
        part[kq][j] = acc;
    }
    __syncthreads();
    if (kq == 0 && j < RANK) {
        float s = ((part[0][j] + part[1][j]) + (part[2][j] + part[3][j]))
                  + b3[d * RANK + j];
        if (d == 0) {
            f01t[n * RANK + j] = s;                      // f0t[a][r]
        } else if (d == 1) {
            f01t[(NPTS + n) * RANK + j] = s;             // f1t[b][r]
        } else {
            f2hi[n * RANK + j] = f2bf_rn(s);             // single-rounded B
        }
    }
}

// ---------------- Phase 2: persistent-block CP via 32x32x16 bf16 MFMA -------
// R14 configuration (empirical optimum, 37.9 us): 1024 blocks x 128 thr
// (2 waves), block owns a c-half staged once (20 KB, XOR-swizzled); per ct:
// 4 ds_read_b128 + 8 MFMAs (A hi/lo x B) + 16 interleaved full-128B-line
// stores. A built in-register with hi/lo split for fp32-grade accuracy.
__global__ __launch_bounds__(128, 2)
void cp_mfma_kernel(const float* __restrict__ f01t,
                    const unsigned short* __restrict__ f2hi,
                    float* __restrict__ out) {
    const int tx = threadIdx.x;
    const int w  = tx >> 6;        // wave -> b sub-tile
    const int l  = tx & 63;
    const int lc = l & 31;         // A row(b) / B col(c) / D col(c)
    const int hw = l >> 5;         // half-wave -> k sub-group

    const int c0 = (blockIdx.x & 1) * CH;

    __shared__ char sB[CH * LROW];   // 20 KB

    // ---- stage c-half of f2 once (1280 float4, 10/thread), swizzled ----
    #pragma unroll
    for (int i = 0; i < 10; ++i) {
        int idx = tx + i * 128;               // 0..1279
        int row = idx >> 3;                   // local c row
        int g   = (idx & 7) << 4;             // 16B slot within 128B row
        *(float4*)(&sB[row * LROW + (g ^ ((row & 7) << 4))]) =
            ((const float4*)f2hi)[c0 * 8 + idx];
    }
    __syncthreads();

    for (int t = blockIdx.x >> 1; t < NPTS * 5; t += 512) {
        const int a   = t / 5;
        const int b0w = (t - a * 5) * 64 + w * 32;
        const float* f0p = f01t + (size_t)a * RANK + hw * 8;
        const float* f1p = f01t + (size_t)(NPTS + b0w + lc) * RANK + hw * 8;

        // ---- A fragments: g[j] = f0[a][k]*f1[b][k], k = ks*16 + hw*8 + j ----
        bf16x8 ahi[4], alo[4];
        #pragma unroll
        for (int ks = 0; ks < 4; ++ks) {
            const int k0 = ks * 16;
            float4 f0a = *(const float4*)(f0p + k0);
            float4 f0b = *(const float4*)(f0p + k0 + 4);
            float4 f1a = *(const float4*)(f1p + k0);
            float4 f1b = *(const float4*)(f1p + k0 + 4);

            float g[8];
            g[0] = f1a.x * f0a.x; g[1] = f1a.y * f0a.y;
            g[2] = f1a.z * f0a.z; g[3] = f1a.w * f0a.w;
            g[4] = f1b.x * f0b.x; g[5] = f1b.y * f0b.y;
            g[6] = f1b.z * f0b.z; g[7] = f1b.w * f0b.w;

            #pragma unroll
            for (int j = 0; j < 8; ++j) {
                unsigned short hi = f2bf_rn(g[j]);
                ahi[ks][j] = (short)hi;
                alo[ks][j] = (short)f2bf_rn(g[j] - bf2f(hi));
            }
        }

        // ---- 5 c-tiles of 32: 4 LDS reads + 8 MFMAs + 16 stores each ----
        #pragma unroll
        for (int ct = 0; ct < 5; ++ct) {
            const char* rowp = &sB[(ct * 32 + lc) * LROW];
            const int swz = ((ct * 32 + lc) & 7) << 4;

            f32x16 acc;
            #pragma unroll
            for (int jj = 0; jj < 16; ++jj) acc[jj] = 0.0f;

            #pragma unroll
            for (int ks = 0; ks < 4; ++ks) {
                const int base = ks * 32 + (hw << 4);       // k slot bytes
                bf16x8 b = *(const bf16x8*)(rowp + (base ^ swz));
                acc = __builtin_amdgcn_mfma_f32_32x32x16_bf16(ahi[ks], b, acc, 0, 0, 0);
                acc = __builtin_amdgcn_mfma_f32_32x32x16_bf16(alo[ks], b, acc, 0, 0, 0);
            }

            // D: col(c)=lc, row(b) = (q&3) + 8*(q>>2) + 4*hw
            float* obase = out + ((size_t)a * NPTS + b0w) * NPTS + c0 + ct * 32 + lc;
            #pragma unroll
            for (int q = 0; q < 16; ++q) {
                int row = (q & 3) + 8 * (q >> 2) + 4 * hw;
                obase[(size_t)row * NPTS] = acc[q];
            }
        }
    }
}

extern "C" void kernel_launch(void* const* d_in, const int* in_sizes, int n_in,
                              void* d_out, int out_size, void* d_ws, size_t ws_size,
                              hipStream_t stream) {
    const float* xs = (const float*)d_in[0];
    const float* W0 = (const float*)d_in[1];
    const float* b0 = (const float*)d_in[2];
    const float* W1 = (const float*)d_in[3];
    const float* b1 = (const float*)d_in[4];
    const float* W2 = (const float*)d_in[5];
    const float* b2 = (const float*)d_in[6];
    const float* W3 = (const float*)d_in[7];
    const float* b3 = (const float*)d_in[8];

    // workspace: f01t float[2][NPTS][RANK] | f2hi ushort[NPTS][RANK]
    float* f01t = (float*)d_ws;
    unsigned short* f2hi = (unsigned short*)((char*)d_ws + 2 * NPTS * RANK * 4);
    float* out = (float*)d_out;

    mlp_kernel<<<dim3(DIMS * NPTS), dim3(512), 0, stream>>>(
        xs, W0, b0, W1, b1, W2, b2, W3, b3, f01t, f2hi);

    cp_mfma_kernel<<<dim3(1024), dim3(128), 0, stream>>>(f01t, f2hi, out);
}